// Round 1
// baseline (6975.870 us; speedup 1.0000x reference)
//
#include <hip/hip_runtime.h>
#include <stdint.h>

typedef uint32_t u32; typedef uint16_t u16;
typedef __attribute__((ext_vector_type(8))) __bf16 bf16x8;
typedef __attribute__((ext_vector_type(4))) float f32x4;
typedef __attribute__((ext_vector_type(4))) u32 u32x4;

#define Vv 50000
#define Ee 256
#define Hh 256
#define Gg 768
#define Bb 64
#define Tt 2048

__device__ __forceinline__ u16 f2bf(float f) {
  u32 x = __builtin_bit_cast(u32, f);
  return (u16)((x + 0x7FFFu + ((x >> 16) & 1u)) >> 16);
}
__device__ __forceinline__ float bf2f(u16 b) {
  u32 x = ((u32)b) << 16;
  return __builtin_bit_cast(float, x);
}
__device__ __forceinline__ u32 pack2(float a, float b) {
  return (u32)f2bf(a) | ((u32)f2bf(b) << 16);
}
__device__ __forceinline__ float sigm(float x) {
  float e = __builtin_amdgcn_exp2f(-1.44269504089f * x);
  return __builtin_amdgcn_rcpf(1.0f + e);
}
__device__ __forceinline__ float tanh_fast(float x) {
  float e = __builtin_amdgcn_exp2f(2.88539008178f * x);
  return 1.0f - 2.0f * __builtin_amdgcn_rcpf(e + 1.0f);
}

// ---------------- K0: zero the "padded token" row ----------------
__global__ void k0_zero(u16* zrow) {
  u32* z = (u32*)zrow;
  for (int i = threadIdx.x; i < 384; i += 256) z[i] = 0;
}

// ---------------- K1: vocab projection P_d[v,g] = sum_e emb[v,e]*W_ih_d[g,e] (bf16 out) ----
__global__ __launch_bounds__(256) void k1_proj(
    const float* __restrict__ emb, const float* __restrict__ Wih_f,
    const float* __restrict__ Wih_b, u16* __restrict__ Pf, u16* __restrict__ Pb)
{
  const int t = threadIdx.x, w = t >> 6, l = t & 63;
  const int cl = l & 15, rq = l >> 4;
  const int m0 = blockIdx.x * 128;
  const int n0 = blockIdx.y * 64;
  const int dir = blockIdx.z;
  const float* Wih = dir ? Wih_b : Wih_f;
  u16* Pd = dir ? Pb : Pf;

  __shared__ u16 As[128 * 40];   // 128 rows x 32 k, stride 40 u16 (80B, 16B-aligned, bank-friendly)
  __shared__ u16 Bs[64 * 40];

  f32x4 zero4 = {0.f, 0.f, 0.f, 0.f};
  f32x4 acc[4][2];
#pragma unroll
  for (int i = 0; i < 4; ++i)
#pragma unroll
    for (int j = 0; j < 2; ++j) acc[i][j] = zero4;

  const int mw = (w >> 1) * 64;   // wave M offset within 128
  const int nw = (w & 1) * 32;    // wave N offset within 64

  for (int kt = 0; kt < 8; ++kt) {
#pragma unroll
    for (int j = 0; j < 4; ++j) {            // stage A: 128x32 f32 -> bf16
      const int flat = t * 4 + j * 1024;
      const int row = flat >> 5, col = flat & 31;
      const int gm = m0 + row;
      float4 v = {0.f, 0.f, 0.f, 0.f};
      if (gm < Vv) v = *(const float4*)(emb + (size_t)gm * Ee + kt * 32 + col);
      u32* d = (u32*)(As + row * 40 + col);
      d[0] = pack2(v.x, v.y);
      d[1] = pack2(v.z, v.w);
    }
#pragma unroll
    for (int j = 0; j < 2; ++j) {            // stage B: 64x32
      const int flat = t * 4 + j * 1024;
      const int row = flat >> 5, col = flat & 31;
      const float4 v = *(const float4*)(Wih + (size_t)(n0 + row) * Ee + kt * 32 + col);
      u32* d = (u32*)(Bs + row * 40 + col);
      d[0] = pack2(v.x, v.y);
      d[1] = pack2(v.z, v.w);
    }
    __syncthreads();
    bf16x8 a[4], bfr[2];
#pragma unroll
    for (int mt = 0; mt < 4; ++mt)
      a[mt] = *(const bf16x8*)(As + (mw + mt * 16 + cl) * 40 + rq * 8);
#pragma unroll
    for (int nt = 0; nt < 2; ++nt)
      bfr[nt] = *(const bf16x8*)(Bs + (nw + nt * 16 + cl) * 40 + rq * 8);
#pragma unroll
    for (int mt = 0; mt < 4; ++mt)
#pragma unroll
      for (int nt = 0; nt < 2; ++nt)
        acc[mt][nt] = __builtin_amdgcn_mfma_f32_16x16x32_bf16(a[mt], bfr[nt], acc[mt][nt], 0, 0, 0);
    __syncthreads();
  }
#pragma unroll
  for (int mt = 0; mt < 4; ++mt)
#pragma unroll
    for (int nt = 0; nt < 2; ++nt)
#pragma unroll
      for (int q = 0; q < 4; ++q) {
        const int row = m0 + mw + mt * 16 + rq * 4 + q;  // C/D: col=lane&15, row=(lane>>4)*4+reg (m89)
        const int col = n0 + nw + nt * 16 + cl;
        if (row < Vv) Pd[(size_t)row * Gg + col] = f2bf(acc[mt][nt][q]);
      }
}

// ---------------- K2: the bidirectional GRU recurrence ----------------
// grid = 8 blocks (dir = blk>>2, batch slice = (blk&3)*16), 512 threads (8 waves), 1 WG/CU.
// W_hh lives in registers as MFMA B-fragments (192 VGPR/lane). h carried in LDS bf16 (2 buffers).
// gi (input projection) gathered from P[token] one step ahead (reg-staged, written after barrier).
__global__ __launch_bounds__(512, 2) void k2_rec(
    const int* __restrict__ seqs, const int* __restrict__ lens,
    const float* __restrict__ Whh_f, const float* __restrict__ Whh_b,
    const float* __restrict__ bih_f, const float* __restrict__ bhh_f,
    const float* __restrict__ bih_b, const float* __restrict__ bhh_b,
    const u16* __restrict__ Pf, const u16* __restrict__ Pb,
    const u16* __restrict__ zrow, float* __restrict__ rep)
{
  const int tid = threadIdx.x;
  const int w = tid >> 6, l = tid & 63;
  const int cl = l & 15, rq = l >> 4;
  const int dir = (int)blockIdx.x >> 2;
  const int b0 = ((int)blockIdx.x & 3) * 16;

  const float* Whh = dir ? Whh_b : Whh_f;
  const float* bih = dir ? bih_b : bih_f;
  const float* bhh = dir ? bhh_b : bhh_f;
  const u16* P = dir ? Pb : Pf;

  __shared__ u16 h_lds[2 * 16 * 264];   // [buf][16 rows][256 + 8 pad] bf16, 528B stride
  __shared__ u16 gi_lds[16 * Gg];       // [16 rows][768] bf16, packed (stage-write target)

  // ---- W_hh B-fragments (persistent registers). Wave w owns unit cols [32w, 32w+32). ----
  bf16x8 wfrag[3][2][8];
#pragma unroll
  for (int g = 0; g < 3; ++g)
#pragma unroll
    for (int bi = 0; bi < 2; ++bi) {
      const int c = g * 256 + (2 * w + bi) * 16 + cl;
      const float* wr = Whh + (size_t)c * Hh;
#pragma unroll
      for (int kb = 0; kb < 8; ++kb) {
        const int k0 = kb * 32 + rq * 8;
        const float4 f0 = *(const float4*)(wr + k0);
        const float4 f1 = *(const float4*)(wr + k0 + 4);
        u32x4 uv = { pack2(f0.x, f0.y), pack2(f0.z, f0.w),
                     pack2(f1.x, f1.y), pack2(f1.z, f1.w) };
        wfrag[g][bi][kb] = __builtin_bit_cast(bf16x8, uv);
      }
    }

  // ---- per-lane biases at this lane's (col) positions ----
  float bias_r[2], bias_z[2], bihn[2], bhhn[2];
#pragma unroll
  for (int bi = 0; bi < 2; ++bi) {
    const int cu = (2 * w + bi) * 16 + cl;
    bias_r[bi] = bih[cu] + bhh[cu];
    bias_z[bi] = bih[256 + cu] + bhh[256 + cu];
    bihn[bi] = bih[512 + cu];
    bhhn[bi] = bhh[512 + cu];
  }

  // wave w stages gi rows 2w, 2w+1
  const int lenA = lens[b0 + 2 * w];
  const int lenB = lens[b0 + 2 * w + 1];
  const int* seqA = seqs + (size_t)(b0 + 2 * w) * Tt;
  const int* seqB = seqs + (size_t)(b0 + 2 * w + 1) * Tt;

  // lane covers bytes [l*16, +16) at offsets 0/1024/2048 of the wave's 3072B (2-row) block
  const int o0 = l * 16, o1 = 1024 + l * 16, o2 = 2048 + l * 16;

  for (int i = tid; i < 16 * 264; i += 512) h_lds[i] = 0;  // h(0) = 0

  // prologue: stage gi(0), prefetch tokens for step 1
  {
    const int t0 = dir ? (Tt - 1) : 0;
    const int tokA0 = seqA[t0], tokB0 = seqB[t0];
    const int vA = dir ? (0 < lenA) : (0 >= Tt - lenA);
    const int vB = dir ? (0 < lenB) : (0 >= Tt - lenB);
    const u16* rA = vA ? (P + (size_t)tokA0 * Gg) : zrow;
    const u16* rB = vB ? (P + (size_t)tokB0 * Gg) : zrow;
    u16* dst = gi_lds + 2 * w * Gg;
    u32x4 g0 = *(const u32x4*)(rA + (o0 >> 1));
    u32x4 g1 = *(const u32x4*)((o1 < 1536) ? (rA + (o1 >> 1)) : (rB + ((o1 - 1536) >> 1)));
    u32x4 g2 = *(const u32x4*)(rB + ((o2 - 1536) >> 1));
    *(u32x4*)(dst + (o0 >> 1)) = g0;
    *(u32x4*)(dst + (o1 >> 1)) = g1;
    *(u32x4*)(dst + (o2 >> 1)) = g2;
  }
  int tokA_nxt = seqA[dir ? (Tt - 2) : 1];
  int tokB_nxt = seqB[dir ? (Tt - 2) : 1];
  __syncthreads();

#pragma unroll 1
  for (int s = 0; s < Tt; ++s) {
    const int par = s & 1;
    const u16* hcur = h_lds + par * (16 * 264);
    u16* hnxt = h_lds + (par ^ 1) * (16 * 264);

    // 1) issue gi(s+1) gather loads (consumed after barrier; latency hidden under MFMA)
    u32x4 g0, g1, g2;
    const bool do_stage = (s + 1 < Tt);
    if (do_stage) {
      const int sn = s + 1;
      const int vA = dir ? (sn < lenA) : (sn >= Tt - lenA);
      const int vB = dir ? (sn < lenB) : (sn >= Tt - lenB);
      const u16* rA = vA ? (P + (size_t)tokA_nxt * Gg) : zrow;
      const u16* rB = vB ? (P + (size_t)tokB_nxt * Gg) : zrow;
      g0 = *(const u32x4*)(rA + (o0 >> 1));
      g1 = *(const u32x4*)((o1 < 1536) ? (rA + (o1 >> 1)) : (rB + ((o1 - 1536) >> 1)));
      g2 = *(const u32x4*)(rB + ((o2 - 1536) >> 1));
    }
    // 2) prefetch tokens for s+2
    int tA2 = tokA_nxt, tB2 = tokB_nxt;
    if (s + 2 < Tt) {
      const int t2 = dir ? (Tt - 1 - (s + 2)) : (s + 2);
      tA2 = seqA[t2];
      tB2 = seqB[t2];
    }

    // 3) gh = h @ W_hh^T (per wave: 2 unit-blocks x 3 gates x K=256) + gates + h'
#pragma unroll
    for (int bi = 0; bi < 2; ++bi) {
      f32x4 ar = {0.f, 0.f, 0.f, 0.f};
      f32x4 az = ar, an = ar;
#pragma unroll
      for (int kb = 0; kb < 8; ++kb) {
        const bf16x8 a = *(const bf16x8*)(hcur + cl * 264 + kb * 32 + rq * 8);
        ar = __builtin_amdgcn_mfma_f32_16x16x32_bf16(a, wfrag[0][bi][kb], ar, 0, 0, 0);
        az = __builtin_amdgcn_mfma_f32_16x16x32_bf16(a, wfrag[1][bi][kb], az, 0, 0, 0);
        an = __builtin_amdgcn_mfma_f32_16x16x32_bf16(a, wfrag[2][bi][kb], an, 0, 0, 0);
      }
      const int cu = (2 * w + bi) * 16 + cl;
#pragma unroll
      for (int q = 0; q < 4; ++q) {
        const int row = rq * 4 + q;
        const u16* gr = gi_lds + row * Gg + cu;
        const float gir = bf2f(gr[0]);
        const float giz = bf2f(gr[256]);
        const float gin = bf2f(gr[512]);
        const float hold = bf2f(hcur[row * 264 + cu]);
        const float r = sigm(gir + bias_r[bi] + ar[q]);
        const float z = sigm(giz + bias_z[bi] + az[q]);
        const float n = tanh_fast(gin + bihn[bi] + r * (an[q] + bhhn[bi]));
        hnxt[row * 264 + cu] = f2bf(n + z * (hold - n));  // (1-z)*n + z*h
      }
    }

    __syncthreads();             // all waves done reading gi_lds / hcur

    if (do_stage) {              // 4) commit gi(s+1) into LDS
      u16* dst = gi_lds + 2 * w * Gg;
      *(u32x4*)(dst + (o0 >> 1)) = g0;
      *(u32x4*)(dst + (o1 >> 1)) = g1;
      *(u32x4*)(dst + (o2 >> 1)) = g2;
    }
    tokA_nxt = tA2;
    tokB_nxt = tB2;
    __syncthreads();             // gi(s+1) + h(s+1) visible to all
  }

  // final h -> rep[b][dir*256 + j]
  const u16* hf_ = h_lds + (Tt & 1) * (16 * 264);
  for (int i = tid; i < 16 * 256; i += 512) {
    const int r = i >> 8, cu = i & 255;
    rep[(size_t)(b0 + r) * (2 * Hh) + dir * Hh + cu] = bf2f(hf_[r * 264 + cu]);
  }
}

// ---------------- K3a: h1 = relu(rep @ W1^T + b1) ----------------
__global__ __launch_bounds__(256) void k3a(
    const float* __restrict__ rep, const float* __restrict__ W1,
    const float* __restrict__ b1, float* __restrict__ h1)
{
  __shared__ float rl[512];
  const int b = blockIdx.x, t = threadIdx.x;
  rl[t] = rep[(size_t)b * 512 + t];
  rl[t + 256] = rep[(size_t)b * 512 + 256 + t];
  __syncthreads();
#pragma unroll
  for (int oo = 0; oo < 2; ++oo) {
    const int o = t + oo * 256;
    const float4* wr = (const float4*)(W1 + (size_t)o * 512);
    const float4* rr = (const float4*)rl;
    float acc = 0.f;
#pragma unroll 8
    for (int k = 0; k < 128; ++k) {
      const float4 wv = wr[k], rv = rr[k];
      acc += wv.x * rv.x + wv.y * rv.y + wv.z * rv.z + wv.w * rv.w;
    }
    h1[(size_t)b * 512 + o] = fmaxf(acc + b1[o], 0.f);
  }
}

// ---------------- K3b: out = softmax(h1 @ W2^T + b2) ----------------
__global__ __launch_bounds__(320) void k3b(
    const float* __restrict__ h1, const float* __restrict__ W2,
    const float* __restrict__ b2, float* __restrict__ out)
{
  __shared__ float lg[64 * 5];
  const int t = threadIdx.x;      // 320 = 5 classes x 64 batch
  const int c = t >> 6, b = t & 63;
  const float4* hr = (const float4*)(h1 + (size_t)b * 512);
  const float4* wr = (const float4*)(W2 + (size_t)c * 512);
  float acc = 0.f;
#pragma unroll 8
  for (int k = 0; k < 128; ++k) {
    const float4 hv = hr[k], wv = wr[k];
    acc += hv.x * wv.x + hv.y * wv.y + hv.z * wv.z + hv.w * wv.w;
  }
  lg[b * 5 + c] = acc + b2[c];
  __syncthreads();
  if (t < 64) {
    float v[5];
#pragma unroll
    for (int i = 0; i < 5; ++i) v[i] = lg[t * 5 + i];
    float m = v[0];
#pragma unroll
    for (int i = 1; i < 5; ++i) m = fmaxf(m, v[i]);
    float ssum = 0.f;
#pragma unroll
    for (int i = 0; i < 5; ++i) {
      v[i] = __builtin_amdgcn_exp2f(1.44269504089f * (v[i] - m));
      ssum += v[i];
    }
    const float inv = 1.0f / ssum;
#pragma unroll
    for (int i = 0; i < 5; ++i) out[t * 5 + i] = v[i] * inv;
  }
}

extern "C" void kernel_launch(void* const* d_in, const int* in_sizes, int n_in,
                              void* d_out, int out_size, void* d_ws, size_t ws_size,
                              hipStream_t stream) {
  const int* seqs = (const int*)d_in[0];
  const int* lens = (const int*)d_in[1];
  const float* emb = (const float*)d_in[2];
  const float* Wih_f = (const float*)d_in[3];
  const float* Whh_f = (const float*)d_in[4];
  const float* bih_f = (const float*)d_in[5];
  const float* bhh_f = (const float*)d_in[6];
  const float* Wih_b = (const float*)d_in[7];
  const float* Whh_b = (const float*)d_in[8];
  const float* bih_b = (const float*)d_in[9];
  const float* bhh_b = (const float*)d_in[10];
  const float* W1 = (const float*)d_in[11];
  const float* b1 = (const float*)d_in[12];
  const float* W2 = (const float*)d_in[13];
  const float* b2 = (const float*)d_in[14];
  float* out = (float*)d_out;

  char* ws = (char*)d_ws;
  u16* Pf = (u16*)ws;                            // 50000*768*2 = 76,800,000 B
  u16* Pb = (u16*)(ws + 76800000LL);             // 76,800,000 B
  u16* zrow = (u16*)(ws + 153600000LL);          // 1536 B (zero "pad token" row)
  float* rep = (float*)(ws + 153601536LL);       // 64*512*4 = 131,072 B
  float* h1 = (float*)(ws + 153732608LL);        // 64*512*4 = 131,072 B

  hipLaunchKernelGGL(k0_zero, dim3(1), dim3(256), 0, stream, zrow);
  hipLaunchKernelGGL(k1_proj, dim3(391, 12, 2), dim3(256), 0, stream,
                     emb, Wih_f, Wih_b, Pf, Pb);
  hipLaunchKernelGGL(k2_rec, dim3(8), dim3(512), 0, stream,
                     seqs, lens, Whh_f, Whh_b, bih_f, bhh_f, bih_b, bhh_b,
                     Pf, Pb, zrow, rep);
  hipLaunchKernelGGL(k3a, dim3(64), dim3(256), 0, stream, rep, W1, b1, h1);
  hipLaunchKernelGGL(k3b, dim3(1), dim3(320), 0, stream, h1, W2, b2, out);
}

// Round 2
// 5103.009 us; speedup vs baseline: 1.3670x; 1.3670x over previous
//
#include <hip/hip_runtime.h>
#include <stdint.h>

typedef uint32_t u32; typedef uint16_t u16;
typedef __attribute__((ext_vector_type(8))) __bf16 bf16x8;
typedef __attribute__((ext_vector_type(4))) float f32x4;
typedef __attribute__((ext_vector_type(2))) u32 u32x2;
typedef __attribute__((ext_vector_type(4))) u32 u32x4;

#define Vv 50000
#define Ee 256
#define Hh 256
#define Gg 768
#define Bb 64
#define Tt 2048

__device__ __forceinline__ u16 f2bf(float f) {
  u32 x = __builtin_bit_cast(u32, f);
  return (u16)((x + 0x7FFFu + ((x >> 16) & 1u)) >> 16);
}
__device__ __forceinline__ float bf2f(u16 b) {
  u32 x = ((u32)b) << 16;
  return __builtin_bit_cast(float, x);
}
__device__ __forceinline__ u32 pack2(float a, float b) {
  return (u32)f2bf(a) | ((u32)f2bf(b) << 16);
}
__device__ __forceinline__ float sigm(float x) {
  float e = __builtin_amdgcn_exp2f(-1.44269504089f * x);
  return __builtin_amdgcn_rcpf(1.0f + e);
}
__device__ __forceinline__ float tanh_fast(float x) {
  float e = __builtin_amdgcn_exp2f(2.88539008178f * x);
  return 1.0f - 2.0f * __builtin_amdgcn_rcpf(e + 1.0f);
}
__device__ __forceinline__ float bfx(u32x2 v, int q) {  // q static after unroll
  u32 word = (q & 2) ? v[1] : v[0];
  u16 h = (q & 1) ? (u16)(word >> 16) : (u16)(word & 0xffffu);
  return bf2f(h);
}

// ---------------- K0: write bias row (row index Vv) of both P tables ----------------
// P'[Vv][c] = bih[c] + (c<512 ? bhh[c] : 0)  == gi of a padded (zero-embedding) step.
__global__ void k0_bias(const float* __restrict__ bih_f, const float* __restrict__ bhh_f,
                        const float* __restrict__ bih_b, const float* __restrict__ bhh_b,
                        u16* __restrict__ Pf, u16* __restrict__ Pb) {
  int c = threadIdx.x + blockIdx.x * 256;
  if (c < Gg) {
    float bf_ = bih_f[c] + (c < 512 ? bhh_f[c] : 0.f);
    float bb_ = bih_b[c] + (c < 512 ? bhh_b[c] : 0.f);
    Pf[(size_t)Vv * Gg + c] = f2bf(bf_);
    Pb[(size_t)Vv * Gg + c] = f2bf(bb_);
  }
}

// ---------------- K1: vocab projection P'[v,g] = emb[v]@W_ih^T + bias (bf16) ----------------
__global__ __launch_bounds__(256) void k1_proj(
    const float* __restrict__ emb, const float* __restrict__ Wih_f,
    const float* __restrict__ Wih_b,
    const float* __restrict__ bih_f, const float* __restrict__ bhh_f,
    const float* __restrict__ bih_b, const float* __restrict__ bhh_b,
    u16* __restrict__ Pf, u16* __restrict__ Pb)
{
  const int t = threadIdx.x, w = t >> 6, l = t & 63;
  const int cl = l & 15, rq = l >> 4;
  const int m0 = blockIdx.x * 128;
  const int n0 = blockIdx.y * 64;
  const int dir = blockIdx.z;
  const float* Wih = dir ? Wih_b : Wih_f;
  const float* bih = dir ? bih_b : bih_f;
  const float* bhh = dir ? bhh_b : bhh_f;
  u16* Pd = dir ? Pb : Pf;

  __shared__ __align__(16) u16 As[128 * 40];
  __shared__ __align__(16) u16 Bs[64 * 40];

  f32x4 zero4 = {0.f, 0.f, 0.f, 0.f};
  f32x4 acc[4][2];
#pragma unroll
  for (int i = 0; i < 4; ++i)
#pragma unroll
    for (int j = 0; j < 2; ++j) acc[i][j] = zero4;

  const int mw = (w >> 1) * 64;
  const int nw = (w & 1) * 32;

  for (int kt = 0; kt < 8; ++kt) {
#pragma unroll
    for (int j = 0; j < 4; ++j) {
      const int flat = t * 4 + j * 1024;
      const int row = flat >> 5, col = flat & 31;
      const int gm = m0 + row;
      float4 v = {0.f, 0.f, 0.f, 0.f};
      if (gm < Vv) v = *(const float4*)(emb + (size_t)gm * Ee + kt * 32 + col);
      u32* d = (u32*)(As + row * 40 + col);
      d[0] = pack2(v.x, v.y);
      d[1] = pack2(v.z, v.w);
    }
#pragma unroll
    for (int j = 0; j < 2; ++j) {
      const int flat = t * 4 + j * 1024;
      const int row = flat >> 5, col = flat & 31;
      const float4 v = *(const float4*)(Wih + (size_t)(n0 + row) * Ee + kt * 32 + col);
      u32* d = (u32*)(Bs + row * 40 + col);
      d[0] = pack2(v.x, v.y);
      d[1] = pack2(v.z, v.w);
    }
    __syncthreads();
    bf16x8 a[4], bfr[2];
#pragma unroll
    for (int mt = 0; mt < 4; ++mt)
      a[mt] = *(const bf16x8*)(As + (mw + mt * 16 + cl) * 40 + rq * 8);
#pragma unroll
    for (int nt = 0; nt < 2; ++nt)
      bfr[nt] = *(const bf16x8*)(Bs + (nw + nt * 16 + cl) * 40 + rq * 8);
#pragma unroll
    for (int mt = 0; mt < 4; ++mt)
#pragma unroll
      for (int nt = 0; nt < 2; ++nt)
        acc[mt][nt] = __builtin_amdgcn_mfma_f32_16x16x32_bf16(a[mt], bfr[nt], acc[mt][nt], 0, 0, 0);
    __syncthreads();
  }
#pragma unroll
  for (int mt = 0; mt < 4; ++mt)
#pragma unroll
    for (int nt = 0; nt < 2; ++nt)
#pragma unroll
      for (int q = 0; q < 4; ++q) {
        const int row = m0 + mw + mt * 16 + rq * 4 + q;
        const int col = n0 + nw + nt * 16 + cl;
        if (row < Vv) {
          const float bias = bih[col] + (col < 512 ? bhh[col] : 0.f);
          Pd[(size_t)row * Gg + col] = f2bf(acc[mt][nt][q] + bias);
        }
      }
}

// ---------------- K2: bidirectional GRU recurrence (transposed MFMA) ----------------
// grid = 8 blocks (dir = blk>>2, batch slice = (blk&3)*16), 512 threads (8 waves), 1 WG/CU.
// D = mfma(A=W_hh frag, B=h frag): m = gate col (wave owns 96 cols = 3 gates x 2 units),
// n = batch row = lane&15. W_hh persistent in 192 VGPRs/lane. h in LDS (double buffer,
// 528B row stride); h' and hold kept in registers. gi gathered per-lane as 6x8B loads.
__global__ __launch_bounds__(512, 1) __attribute__((amdgpu_waves_per_eu(2)))
void k2_rec(
    const int* __restrict__ seqs, const int* __restrict__ lens,
    const float* __restrict__ Whh_f, const float* __restrict__ Whh_b,
    const float* __restrict__ bhh_f, const float* __restrict__ bhh_b,
    const u16* __restrict__ Pf, const u16* __restrict__ Pb,
    float* __restrict__ rep)
{
  const int tid = threadIdx.x;
  const int w = tid >> 6, l = tid & 63;
  const int cl = l & 15, rq = l >> 4;
  const int dir = (int)blockIdx.x >> 2;
  const int b0 = ((int)blockIdx.x & 3) * 16;

  const float* Whh = dir ? Whh_b : Whh_f;
  const float* bhh = dir ? bhh_b : bhh_f;
  const u16* P = dir ? Pb : Pf;

  __shared__ __align__(16) u16 h_lds[2 * 16 * 264];  // [buf][16 rows][256+8 pad]

  // ---- W_hh A-fragments (persistent). A[m = gcol][k]: gcol = g*256+(2w+bi)*16+cl ----
  bf16x8 wfrag[3][2][8];
#pragma unroll
  for (int g = 0; g < 3; ++g)
#pragma unroll
    for (int bi = 0; bi < 2; ++bi) {
      const int c = g * 256 + (2 * w + bi) * 16 + cl;
      const float* wr = Whh + (size_t)c * Hh;
#pragma unroll
      for (int kb = 0; kb < 8; ++kb) {
        const int k0 = kb * 32 + rq * 8;
        const float4 f0 = *(const float4*)(wr + k0);
        const float4 f1 = *(const float4*)(wr + k0 + 4);
        u32x4 uv = { pack2(f0.x, f0.y), pack2(f0.z, f0.w),
                     pack2(f1.x, f1.y), pack2(f1.z, f1.w) };
        wfrag[g][bi][kb] = __builtin_bit_cast(bf16x8, uv);
      }
    }

  // b_hh_n at this lane's n-gate cols: 512 + (2w+bi)*16 + rq*4 + q
  float bhhn[2][4];
#pragma unroll
  for (int bi = 0; bi < 2; ++bi)
#pragma unroll
    for (int q = 0; q < 4; ++q)
      bhhn[bi][q] = bhh[512 + (2 * w + bi) * 16 + rq * 4 + q];

  // hold/h' registers: position (row=cl, col=(2w+bi)*16+rq*4+q)
  float hprev[2][4];
#pragma unroll
  for (int bi = 0; bi < 2; ++bi)
#pragma unroll
    for (int q = 0; q < 4; ++q) hprev[bi][q] = 0.f;

  // this lane's batch row (for gi gather): cl
  const int myrow = b0 + cl;
  const int mylen = lens[myrow];
  const int* myseq = seqs + (size_t)myrow * Tt;

  for (int i = tid; i < 16 * 264; i += 512) h_lds[i] = 0;  // h(0)=0 in buf0

  // prologue: gi(0) into registers
  u32x2 gi[3][2];
  {
    const int tok0 = myseq[dir ? (Tt - 1) : 0];
    const int valid0 = dir ? (0 < mylen) : (0 >= Tt - mylen);
    const size_t vrow = valid0 ? (size_t)tok0 : (size_t)Vv;
#pragma unroll
    for (int bi = 0; bi < 2; ++bi) {
      const u16* pr = P + vrow * Gg + (2 * w + bi) * 16 + rq * 4;
#pragma unroll
      for (int g = 0; g < 3; ++g) gi[g][bi] = *(const u32x2*)(pr + g * 256);
    }
  }
  __syncthreads();

  const int rdbase = cl * 264 + rq * 8;
  const int wrbase = cl * 264 + 2 * w * 16 + rq * 4;

  for (int s = 0; s < Tt; ++s) {
    const int par = s & 1;
    const u16* hb = h_lds + par * (16 * 264);
    u16* hn = h_lds + (par ^ 1) * (16 * 264);

    // 1) prefetch token for step s+1 (latency hidden under MFMA phase)
    int tok1 = 0;
    const bool more = (s + 1 < Tt);
    if (more) tok1 = myseq[dir ? (Tt - 2 - s) : (s + 1)];

    // 2) gh^T = W_hh · h^T : stream h B-fragments, MFMA into 6 accumulators
    f32x4 acc[3][2];
    f32x4 z4 = {0.f, 0.f, 0.f, 0.f};
#pragma unroll
    for (int g = 0; g < 3; ++g)
#pragma unroll
      for (int bi = 0; bi < 2; ++bi) acc[g][bi] = z4;

    bf16x8 bA = *(const bf16x8*)(hb + rdbase);
    bf16x8 bB;
#pragma unroll
    for (int kb = 0; kb < 8; kb += 2) {
      bB = *(const bf16x8*)(hb + rdbase + (kb + 1) * 32);
#pragma unroll
      for (int g = 0; g < 3; ++g)
#pragma unroll
        for (int bi = 0; bi < 2; ++bi)
          acc[g][bi] = __builtin_amdgcn_mfma_f32_16x16x32_bf16(wfrag[g][bi][kb], bA, acc[g][bi], 0, 0, 0);
      if (kb + 2 < 8) bA = *(const bf16x8*)(hb + rdbase + (kb + 2) * 32);
#pragma unroll
      for (int g = 0; g < 3; ++g)
#pragma unroll
        for (int bi = 0; bi < 2; ++bi)
          acc[g][bi] = __builtin_amdgcn_mfma_f32_16x16x32_bf16(wfrag[g][bi][kb + 1], bB, acc[g][bi], 0, 0, 0);
    }

    // 3) gates + h' (registers), write h' as 2 x b64, reissue gi loads for s+1
#pragma unroll
    for (int bi = 0; bi < 2; ++bi) {
      float hq[4];
#pragma unroll
      for (int q = 0; q < 4; ++q) {
        const float ir = bfx(gi[0][bi], q);            // includes b_ih_r + b_hh_r
        const float iz = bfx(gi[1][bi], q);            // includes b_ih_z + b_hh_z
        const float in_ = bfx(gi[2][bi], q);           // includes b_ih_n
        const float r = sigm(ir + acc[0][bi][q]);
        const float z = sigm(iz + acc[1][bi][q]);
        const float n = tanh_fast(in_ + r * (acc[2][bi][q] + bhhn[bi][q]));
        const float hv = n + z * (hprev[bi][q] - n);   // (1-z)*n + z*h
        hprev[bi][q] = hv;
        hq[q] = hv;
      }
      u32x2 hw = { pack2(hq[0], hq[1]), pack2(hq[2], hq[3]) };
      *(u32x2*)(hn + wrbase + bi * 16) = hw;

      if (more) {  // gi(s+1) for this bi-group (regs just freed)
        const int sn = s + 1;
        const int valid1 = dir ? (sn < mylen) : (sn >= Tt - mylen);
        const size_t vrow = valid1 ? (size_t)tok1 : (size_t)Vv;
        const u16* pr = P + vrow * Gg + (2 * w + bi) * 16 + rq * 4;
#pragma unroll
        for (int g = 0; g < 3; ++g) gi[g][bi] = *(const u32x2*)(pr + g * 256);
      }
    }

    __syncthreads();   // h(s+1) visible; (also drains gi loads - acceptable)
  }

  // final h -> rep[b][dir*256 + col], straight from registers
#pragma unroll
  for (int bi = 0; bi < 2; ++bi)
#pragma unroll
    for (int q = 0; q < 4; ++q) {
      const int col = (2 * w + bi) * 16 + rq * 4 + q;
      rep[(size_t)(b0 + cl) * (2 * Hh) + dir * Hh + col] = hprev[bi][q];
    }
}

// ---------------- K3a: h1 = relu(rep @ W1^T + b1) ----------------
__global__ __launch_bounds__(256) void k3a(
    const float* __restrict__ rep, const float* __restrict__ W1,
    const float* __restrict__ b1, float* __restrict__ h1)
{
  __shared__ float rl[512];
  const int b = blockIdx.x, t = threadIdx.x;
  rl[t] = rep[(size_t)b * 512 + t];
  rl[t + 256] = rep[(size_t)b * 512 + 256 + t];
  __syncthreads();
#pragma unroll
  for (int oo = 0; oo < 2; ++oo) {
    const int o = t + oo * 256;
    const float4* wr = (const float4*)(W1 + (size_t)o * 512);
    const float4* rr = (const float4*)rl;
    float acc = 0.f;
#pragma unroll 8
    for (int k = 0; k < 128; ++k) {
      const float4 wv = wr[k], rv = rr[k];
      acc += wv.x * rv.x + wv.y * rv.y + wv.z * rv.z + wv.w * rv.w;
    }
    h1[(size_t)b * 512 + o] = fmaxf(acc + b1[o], 0.f);
  }
}

// ---------------- K3b: out = softmax(h1 @ W2^T + b2) ----------------
__global__ __launch_bounds__(320) void k3b(
    const float* __restrict__ h1, const float* __restrict__ W2,
    const float* __restrict__ b2, float* __restrict__ out)
{
  __shared__ float lg[64 * 5];
  const int t = threadIdx.x;      // 320 = 5 classes x 64 batch
  const int c = t >> 6, b = t & 63;
  const float4* hr = (const float4*)(h1 + (size_t)b * 512);
  const float4* wr = (const float4*)(W2 + (size_t)c * 512);
  float acc = 0.f;
#pragma unroll 8
  for (int k = 0; k < 128; ++k) {
    const float4 hv = hr[k], wv = wr[k];
    acc += hv.x * wv.x + hv.y * wv.y + hv.z * wv.z + hv.w * wv.w;
  }
  lg[b * 5 + c] = acc + b2[c];
  __syncthreads();
  if (t < 64) {
    float v[5];
#pragma unroll
    for (int i = 0; i < 5; ++i) v[i] = lg[t * 5 + i];
    float m = v[0];
#pragma unroll
    for (int i = 1; i < 5; ++i) m = fmaxf(m, v[i]);
    float ssum = 0.f;
#pragma unroll
    for (int i = 0; i < 5; ++i) {
      v[i] = __builtin_amdgcn_exp2f(1.44269504089f * (v[i] - m));
      ssum += v[i];
    }
    const float inv = 1.0f / ssum;
#pragma unroll
    for (int i = 0; i < 5; ++i) out[t * 5 + i] = v[i] * inv;
  }
}

extern "C" void kernel_launch(void* const* d_in, const int* in_sizes, int n_in,
                              void* d_out, int out_size, void* d_ws, size_t ws_size,
                              hipStream_t stream) {
  const int* seqs = (const int*)d_in[0];
  const int* lens = (const int*)d_in[1];
  const float* emb = (const float*)d_in[2];
  const float* Wih_f = (const float*)d_in[3];
  const float* Whh_f = (const float*)d_in[4];
  const float* bih_f = (const float*)d_in[5];
  const float* bhh_f = (const float*)d_in[6];
  const float* Wih_b = (const float*)d_in[7];
  const float* Whh_b = (const float*)d_in[8];
  const float* bih_b = (const float*)d_in[9];
  const float* bhh_b = (const float*)d_in[10];
  const float* W1 = (const float*)d_in[11];
  const float* b1 = (const float*)d_in[12];
  const float* W2 = (const float*)d_in[13];
  const float* b2 = (const float*)d_in[14];
  float* out = (float*)d_out;

  char* ws = (char*)d_ws;
  const size_t PSZ = (size_t)(Vv + 1) * Gg * 2;   // 76,801,536 B per direction
  u16* Pf = (u16*)ws;
  u16* Pb = (u16*)(ws + PSZ);
  float* rep = (float*)(ws + 2 * PSZ);            // 64*512*4 = 131,072 B
  float* h1 = (float*)(ws + 2 * PSZ + 131072);

  hipLaunchKernelGGL(k0_bias, dim3(3), dim3(256), 0, stream,
                     bih_f, bhh_f, bih_b, bhh_b, Pf, Pb);
  hipLaunchKernelGGL(k1_proj, dim3(391, 12, 2), dim3(256), 0, stream,
                     emb, Wih_f, Wih_b, bih_f, bhh_f, bih_b, bhh_b, Pf, Pb);
  hipLaunchKernelGGL(k2_rec, dim3(8), dim3(512), 0, stream,
                     seqs, lens, Whh_f, Whh_b, bhh_f, bhh_b, Pf, Pb, rep);
  hipLaunchKernelGGL(k3a, dim3(64), dim3(256), 0, stream, rep, W1, b1, h1);
  hipLaunchKernelGGL(k3b, dim3(1), dim3(320), 0, stream, h1, W2, b2, out);
}